// Round 11
// baseline (703.312 us; speedup 1.0000x reference)
//
#include <hip/hip_runtime.h>
#include <hip/hip_bf16.h>
#include <cstdint>
#include <cstddef>

typedef unsigned short u16;
typedef __attribute__((ext_vector_type(8))) __bf16 bf16x8;
typedef __attribute__((ext_vector_type(4))) float f32x4;
typedef __attribute__((ext_vector_type(8))) unsigned short us8;

#define NDM 768
#define NDI 3072
#define NTT 1024
#define NBB 16
#define NM (NBB*NTT)   // 16384 rows total

// ---------- helpers ----------
__device__ __forceinline__ u16 f2bf(float f) {
  unsigned u = __builtin_bit_cast(unsigned, f);
  u += 0x7fffu + ((u >> 16) & 1u);          // RNE
  return (u16)(u >> 16);
}
__device__ __forceinline__ float bf2f(u16 b) {
  return __builtin_bit_cast(float, ((unsigned)b) << 16);
}
__device__ __forceinline__ float silu_f(float v) {
  return v * (1.0f / (1.0f + __expf(-v)));
}
__device__ __forceinline__ void gload16(const u16* g, u16* l) {
  __builtin_amdgcn_global_load_lds((const __attribute__((address_space(1))) void*)g,
                                   (__attribute__((address_space(3))) void*)l, 16, 0, 0);
}

// ---------- fp32 -> bf16 convert ----------
__global__ __launch_bounds__(256)
void k_f32_to_bf16(const float* __restrict__ in, u16* __restrict__ out, int n4) {
  const int i = blockIdx.x * 256 + threadIdx.x;
  if (i < n4) {
    float4 v = ((const float4*)in)[i];
    ushort4 o;
    o.x = f2bf(v.x); o.y = f2bf(v.y); o.z = f2bf(v.z); o.w = f2bf(v.w);
    ((ushort4*)out)[i] = o;
  }
}

// conv_w [E][3][3] -> wTb [9][E] (bf16)
__global__ __launch_bounds__(256)
void k_convw_t(const float* __restrict__ cw, u16* __restrict__ wTb) {
  const int e = blockIdx.x * 256 + threadIdx.x;
  if (e < NDI) {
#pragma unroll
    for (int t = 0; t < 9; t++) wTb[t * NDI + e] = f2bf(cw[e * 9 + t]);
  }
}

// ---------- RMSNorm: x[M,768] f32 -> h[M,768] bf16 ----------
__global__ __launch_bounds__(256)
void k_rmsnorm(const float* __restrict__ x, const float* __restrict__ w, u16* __restrict__ h) {
  const int row  = blockIdx.x * 4 + (threadIdx.x >> 6);
  const int lane = threadIdx.x & 63;
  const float4* xr = (const float4*)(x + (size_t)row * NDM);
  float4 a = xr[lane], b = xr[lane + 64], c = xr[lane + 128];
  float ss = a.x*a.x + a.y*a.y + a.z*a.z + a.w*a.w
           + b.x*b.x + b.y*b.y + b.z*b.z + b.w*b.w
           + c.x*c.x + c.y*c.y + c.z*c.z + c.w*c.w;
#pragma unroll
  for (int off = 32; off > 0; off >>= 1) ss += __shfl_xor(ss, off);
  const float r = rsqrtf(ss * (1.0f / NDM) + 1e-5f);
  const float4* wr = (const float4*)w;
  float4 wa = wr[lane], wb = wr[lane + 64], wc = wr[lane + 128];
  ushort4 oa, ob, oc;
  oa.x = f2bf(a.x * r * wa.x); oa.y = f2bf(a.y * r * wa.y);
  oa.z = f2bf(a.z * r * wa.z); oa.w = f2bf(a.w * r * wa.w);
  ob.x = f2bf(b.x * r * wb.x); ob.y = f2bf(b.y * r * wb.y);
  ob.z = f2bf(b.z * r * wb.z); ob.w = f2bf(b.w * r * wb.w);
  oc.x = f2bf(c.x * r * wc.x); oc.y = f2bf(c.y * r * wc.y);
  oc.z = f2bf(c.z * r * wc.z); oc.w = f2bf(c.w * r * wc.w);
  ushort4* hr = (ushort4*)(h + (size_t)row * NDM);
  hr[lane] = oa; hr[lane + 64] = ob; hr[lane + 128] = oc;
}

// ---------- 256x256-tile, BK=32 sub-tiles, ring-4 LDS, depth-3 prefetch, 8-wave GEMM ----------
// Pipeline (T3+T4+T5): per sub-tile s: counted vmcnt -> barrier -> 12 ds_read_b128 ->
// issue stage(s+3) (overwrites buf consumed in iter s-1; safe: all waves' reads of it
// completed before reaching this barrier via MFMA operand dependence) -> setprio(1),
// 32 MFMA, setprio(0).  vmcnt ledger: prologue stages s0,s1,s2 (12 outstanding);
// iter s waits vmcnt(8) (completes s, leaves s+1,s+2); tail vmcnt(4)/vmcnt(0).
// LDS: A ring [4][256][32] bf16 at 0 (32KB), B same at +32768 u16 -> 128 KiB.
// Swizzle (both-sides involution, rule 21): 16B-slot p at row r holds logical p^(r&3);
// staged via pre-swizzled GLOBAL source (linear gload dest), read with matching XOR.
// Bank occupancy: uniform 2-way (free, m136).
// MODE 0: bf16 -> C0 stride N.  MODE 2: bf16 * expf(*scalep)/1024 -> C0.
// MODE 3: f32 -> C0 = X + bf16(C1) + acc.  MODE 5: col<3072 -> C0; else silu -> C1.
template <int MODE>
__global__ __launch_bounds__(512, 2)
void k_g8(const u16* __restrict__ A, const u16* __restrict__ B,
          void* __restrict__ C0, void* __restrict__ C1,
          const float* __restrict__ X, const float* __restrict__ scalep,
          int N, int Kd, int nst, int nTiles,
          long sAb, long sBb, long sCb, int mPerBatchB, long sBm) {
  __shared__ u16 smem[65536];                        // 128 KiB
  const int bz = blockIdx.z;
  A += (size_t)bz * sAb;
  B += (size_t)bz * sBb;
  const int nwg = gridDim.x;
  const int id = blockIdx.x;
  const int sid = ((nwg & 7) == 0) ? ((id & 7) * (nwg >> 3) + (id >> 3)) : id;
  const int mt = sid / nTiles, ntile = sid - mt * nTiles;
  const int m0 = mt * 256, n0 = ntile * 256;
  if (mPerBatchB > 0) B += (size_t)(m0 / mPerBatchB) * sBm;

  const int tid = threadIdx.x;
  const int lane = tid & 63, wid = tid >> 6;
  const int wm = wid >> 2, wn = wid & 3;             // 2 (M) x 4 (N) waves
  const int fr = lane & 15, l4 = lane >> 4;

  // staging per-thread constants: issue i covers row = i*128 + rbase, phys slot = lane&3,
  // logical 16B-slot = (lane&3) ^ (row&3), row&3 == (lane>>2)&3
  const int rbase = (wid << 4) + (lane >> 2);        // 0..127
  const int cslot = (lane & 3) ^ ((lane >> 2) & 3);
  const u16* Ap = A + (size_t)(m0 + rbase) * Kd + cslot * 8;
  const u16* Bp = B + (size_t)(n0 + rbase) * Kd + cslot * 8;
  const size_t strideI = (size_t)128 * Kd;           // +128 rows for issue 1
  const int ldsW = wid * 512;                        // wave-uniform dest base (u16)

#define STAGE_G8(s_) {                                         \
    const int b3_ = (s_) & 3;                                  \
    const u16* as_ = Ap + (size_t)(s_) * 32;                   \
    const u16* bs_ = Bp + (size_t)(s_) * 32;                   \
    u16* ad_ = smem + b3_ * 8192 + ldsW;                       \
    u16* bd_ = smem + 32768 + b3_ * 8192 + ldsW;               \
    gload16(as_, ad_);           gload16(as_ + strideI, ad_ + 4096); \
    gload16(bs_, bd_);           gload16(bs_ + strideI, bd_ + 4096); }

  f32x4 acc[8][4];
#pragma unroll
  for (int m = 0; m < 8; m++)
#pragma unroll
    for (int n = 0; n < 4; n++) acc[m][n] = (f32x4){0.f, 0.f, 0.f, 0.f};

  STAGE_G8(0); STAGE_G8(1); STAGE_G8(2);             // depth-3 prologue (12 outstanding)

#pragma unroll 1
  for (int s = 0; s < nst; s++) {
    const int left = nst - 1 - s;
    if (left >= 2)      asm volatile("s_waitcnt vmcnt(8)" ::: "memory");
    else if (left == 1) asm volatile("s_waitcnt vmcnt(4)" ::: "memory");
    else                asm volatile("s_waitcnt vmcnt(0)" ::: "memory");
    __builtin_amdgcn_s_barrier();                    // buf[s&3] staged; prev reads done chip-wide
    __builtin_amdgcn_sched_barrier(0);               // pin: nothing moves above the barrier

    const int b = s & 3;
    const u16* Ab = smem + b * 8192;
    const u16* Bb = smem + 32768 + b * 8192;

    bf16x8 bfr[4];
#pragma unroll
    for (int nf = 0; nf < 4; nf++) {
      const int brow = wn * 64 + nf * 16 + fr;
      bfr[nf] = *(const bf16x8*)&Bb[brow * 32 + ((l4 ^ (brow & 3)) << 3)];
    }
    bf16x8 af[8];
#pragma unroll
    for (int mf = 0; mf < 8; mf++) {
      const int arow = wm * 128 + mf * 16 + fr;
      af[mf] = *(const bf16x8*)&Ab[arow * 32 + ((l4 ^ (arow & 3)) << 3)];
    }

    if (s + 3 < nst) STAGE_G8(s + 3);                // issue早 -> HBM latency hides under MFMA

    __builtin_amdgcn_s_setprio(1);
#pragma unroll
    for (int mf = 0; mf < 8; mf++)
#pragma unroll
      for (int nf = 0; nf < 4; nf++)
        acc[mf][nf] = __builtin_amdgcn_mfma_f32_16x16x32_bf16(af[mf], bfr[nf], acc[mf][nf], 0, 0, 0);
    __builtin_amdgcn_s_setprio(0);
  }
#undef STAGE_G8

  // ---- epilogue ----
  float sc = 1.0f;
  if (MODE == 2) sc = __expf(scalep[0]) * (1.0f / 1024.0f);
  const size_t cb = (size_t)bz * sCb;
#pragma unroll
  for (int mf = 0; mf < 8; mf++) {
#pragma unroll
    for (int nf = 0; nf < 4; nf++) {
      const int lc = wn * 64 + nf * 16 + fr;
      const int rb = m0 + wm * 128 + mf * 16 + (l4 << 2);
#pragma unroll
      for (int q = 0; q < 4; q++) {
        float v = acc[mf][nf][q];
        if (MODE == 0) {
          ((u16*)C0)[cb + (size_t)(rb + q) * N + n0 + lc] = f2bf(v);
        } else if (MODE == 2) {
          ((u16*)C0)[cb + (size_t)(rb + q) * N + n0 + lc] = f2bf(v * sc);
        } else if (MODE == 3) {
          const size_t idx = (size_t)(rb + q) * N + n0 + lc;
          ((float*)C0)[idx] = X[idx] + bf2f(((const u16*)C1)[idx]) + v;
        } else { // MODE 5
          const int gc = n0 + lc;
          if (gc < 3072) ((u16*)C0)[(size_t)(rb + q) * 3072 + gc] = f2bf(v);
          else           ((u16*)C1)[(size_t)(rb + q) * 3072 + gc - 3072] = f2bf(silu_f(v));
        }
      }
    }
  }
}

// ---------- depthwise 3x3 conv + bias + silu, * pre-silu'd gate, in-place into gate ----------
__global__ __launch_bounds__(384)
void k_conv_gate(const u16* __restrict__ val, u16* __restrict__ gate,
                 const u16* __restrict__ wTb, const float* __restrict__ bias) {
  const int tid = threadIdx.x;
  const int m = blockIdx.x * 2 + (tid >= 192);
  const int e0 = (tid % 192) * 16;
  const int j = m & 31, i = (m >> 5) & 31;
  float acc[16];
  {
    const float4* bp = (const float4*)(bias + e0);
    float4 b0 = bp[0], b1 = bp[1], b2 = bp[2], b3 = bp[3];
    acc[0]=b0.x; acc[1]=b0.y; acc[2]=b0.z; acc[3]=b0.w;
    acc[4]=b1.x; acc[5]=b1.y; acc[6]=b1.z; acc[7]=b1.w;
    acc[8]=b2.x; acc[9]=b2.y; acc[10]=b2.z; acc[11]=b2.w;
    acc[12]=b3.x; acc[13]=b3.y; acc[14]=b3.z; acc[15]=b3.w;
  }
  const u16* vb = val + (size_t)m * NDI + e0;
#pragma unroll
  for (int di = -1; di <= 1; di++) {
    if ((unsigned)(i + di) >= 32u) continue;
#pragma unroll
    for (int dj = -1; dj <= 1; dj++) {
      if ((unsigned)(j + dj) >= 32u) continue;
      const u16* vp = vb + (ptrdiff_t)(di * 32 + dj) * NDI;
      us8 v0 = *(const us8*)vp, v1 = *(const us8*)(vp + 8);
      const u16* wp = wTb + ((di + 1) * 3 + (dj + 1)) * NDI + e0;
      us8 w0 = *(const us8*)wp, w1 = *(const us8*)(wp + 8);
#pragma unroll
      for (int q = 0; q < 8; q++) acc[q]     += bf2f(v0[q]) * bf2f(w0[q]);
#pragma unroll
      for (int q = 0; q < 8; q++) acc[8 + q] += bf2f(v1[q]) * bf2f(w1[q]);
    }
  }
  u16* gp = gate + (size_t)m * NDI + e0;
  us8 g0 = *(const us8*)gp, g1 = *(const us8*)(gp + 8);
  us8 o0, o1;
#pragma unroll
  for (int q = 0; q < 8; q++) o0[q] = f2bf(silu_f(acc[q]) * bf2f(g0[q]));
#pragma unroll
  for (int q = 0; q < 8; q++) o1[q] = f2bf(silu_f(acc[8 + q]) * bf2f(g1[q]));
  *(us8*)gp = o0;
  *(us8*)(gp + 8) = o1;
}

// ---------- bf16 transpose: in [NB][NT][NDM] -> out [NB][NDM][NT] ----------
__global__ __launch_bounds__(256)
void k_transpose(const u16* __restrict__ in, u16* __restrict__ out) {
  __shared__ u16 tile[64][65];
  const int d0 = blockIdx.x * 64, t0 = blockIdx.y * 64, b = blockIdx.z;
  const int lx = threadIdx.x & 15, ly = threadIdx.x >> 4;
  const u16* ip = in + ((size_t)b * NTT + t0) * NDM + d0;
#pragma unroll
  for (int p = 0; p < 4; p++) {
    const int r = ly + p * 16;
    ushort4 v = *(const ushort4*)(ip + (size_t)r * NDM + lx * 4);
    tile[r][lx * 4 + 0] = v.x; tile[r][lx * 4 + 1] = v.y;
    tile[r][lx * 4 + 2] = v.z; tile[r][lx * 4 + 3] = v.w;
  }
  __syncthreads();
  u16* op = out + ((size_t)b * NDM + d0) * NTT + t0;
#pragma unroll
  for (int p = 0; p < 4; p++) {
    const int r = ly + p * 16;
    ushort4 v;
    v.x = tile[lx * 4 + 0][r]; v.y = tile[lx * 4 + 1][r];
    v.z = tile[lx * 4 + 2][r]; v.w = tile[lx * 4 + 3][r];
    *(ushort4*)(op + (size_t)r * NTT + lx * 4) = v;
  }
}

// ---------- launch ----------
extern "C" void kernel_launch(void* const* d_in, const int* in_sizes, int n_in,
                              void* d_out, int out_size, void* d_ws, size_t ws_size,
                              hipStream_t stream) {
  const float* x      = (const float*)d_in[0];
  const float* norm_w = (const float*)d_in[1];
  const float* w_proj = (const float*)d_in[2];
  const float* w_gate = (const float*)d_in[3];
  const float* conv_w = (const float*)d_in[4];
  const float* conv_b = (const float*)d_in[5];
  const float* w_out  = (const float*)d_in[6];
  const float* w_k    = (const float*)d_in[7];
  const float* w_v    = (const float*)d_in[8];
  const float* lalpha = (const float*)d_in[9];

  // d_out as scratch for h + bf16 weights (all dead before final GEMM writes d_out)
  char* ob = (char*)d_out;
  u16* h    = (u16*)(ob);                    // 25,165,824 B
  u16* wcat = (u16*)(ob + 25165824);         //  9,437,184  [w_proj ; w_gate] (6144 x 768)
  u16* wob  = (u16*)(ob + 34603008);         //  4,718,592
  u16* wkb  = (u16*)(ob + 39321600);         //  1,179,648
  u16* wvb  = (u16*)(ob + 40501248);         //  1,179,648
  u16* wTb  = (u16*)(ob + 41680896);         //     55,296  (total 41.7MB < 50.3MB)

  char* ws = (char*)d_ws;
  u16* valp  = (u16*)(ws);                   // 100,663,296  [dead after conv]
  u16* gateb = (u16*)(ws + 100663296);       // 100,663,296  silu(gate)->gated [dead after out GEMM]
  u16* outb  = (u16*)(ws);                   //  25,165,824  (valp region, valp dead)
  u16* Kbf   = (u16*)(ws + 25165824);        //  25,165,824
  u16* Vbf   = (u16*)(ws + 50331648);        //  25,165,824
  u16* Kt    = (u16*)(ws + 100663296);       //  25,165,824  (gateb region, gateb dead)
  u16* Vt    = (u16*)(ws + 125829120);       //  25,165,824
  u16* Wt    = (u16*)(ws + 150994944);       //  18,874,368  (max used 169.9MB)

  // weight preprocessing
  k_f32_to_bf16<<<2304, 256, 0, stream>>>(w_proj, wcat,           589824);
  k_f32_to_bf16<<<2304, 256, 0, stream>>>(w_gate, wcat + 2359296, 589824);
  k_f32_to_bf16<<<2304, 256, 0, stream>>>(w_out,  wob, 589824);
  k_f32_to_bf16<<<576,  256, 0, stream>>>(w_k,    wkb, 147456);
  k_f32_to_bf16<<<576,  256, 0, stream>>>(w_v,    wvb, 147456);
  k_convw_t<<<12, 256, 0, stream>>>(conv_w, wTb);

  // h = rmsnorm(x) in bf16
  k_rmsnorm<<<4096, 256, 0, stream>>>(x, norm_w, h);

  // [val_pre | silu(gate_pre)] = h @ [w_proj;w_gate]^T  (M=16384, N=6144, K=768, nst=24)
  k_g8<5><<<1536, 512, 0, stream>>>(h, wcat, valp, gateb, nullptr, nullptr,
                                    3072, 768, 24, 24, 0, 0, 0, 0, 0);
  // gated = silu(conv(val_pre)+b) * siluGate   (in-place into gateb)
  k_conv_gate<<<8192, 384, 0, stream>>>(valp, gateb, wTb, conv_b);

  // out = gated @ w_out^T  (M=16384, N=768, K=3072, nst=96)
  k_g8<0><<<192, 512, 0, stream>>>(gateb, wob, outb, nullptr, nullptr, nullptr,
                                   768, 3072, 96, 3, 0, 0, 0, 0, 0);
  // K = h @ w_k^T ; V = out @ w_v^T  (K=768, nst=24)
  k_g8<0><<<192, 512, 0, stream>>>(h, wkb, Kbf, nullptr, nullptr, nullptr,
                                   768, 768, 24, 3, 0, 0, 0, 0, 0);
  k_g8<0><<<192, 512, 0, stream>>>(outb, wvb, Vbf, nullptr, nullptr, nullptr,
                                   768, 768, 24, 3, 0, 0, 0, 0, 0);
  // K^T, V^T per batch: [B, D, T]
  k_transpose<<<dim3(12, 16, 16), 256, 0, stream>>>(Kbf, Kt);
  k_transpose<<<dim3(12, 16, 16), 256, 0, stream>>>(Vbf, Vt);

  // Wt[b][e][d] = (alpha/T) * sum_t V[t,e] K[t,d]  (per-batch 768x768, K=1024, nst=32)
  k_g8<2><<<dim3(9, 1, 16), 512, 0, stream>>>(Vt, Kt, Wt, nullptr, nullptr, lalpha,
                                              768, 1024, 32, 3,
                                              (long)NDM * NTT, (long)NDM * NTT,
                                              (long)NDM * NDM, 0, 0);
  // final: d_out = x + out + sum_d K[t,d] * Wt[e,d]  (K=768, nst=24, per-batch B)
  k_g8<3><<<192, 512, 0, stream>>>(Kbf, Wt, d_out, outb, x, nullptr,
                                   768, 768, 24, 3, 0, 0, 0,
                                   NTT, (long)NDM * NDM);
}